// Round 3
// baseline (2309.701 us; speedup 1.0000x reference)
//
#include <hip/hip_runtime.h>

// ASIF multi-head attention + HIE, MI355X (gfx950). ALL I/O fp32.
// B=256, S=200, D=256, H=4, HD=64, R=16.
// 5 fp32 arenas: W0,W1 in d_ws (needs 104.9MB, verified available),
// O0,O1,O2 = thirds of d_out (157MB). HIE chain fp32/double throughout
// (indicator-gate chaos demands it).

constexpr int B_ = 256, S_ = 200, D_ = 256, H_ = 4, R_ = 16;
constexpr int M_ = B_ * S_;                    // 51200
constexpr size_t BSD = (size_t)B_ * S_ * D_;   // 13,107,200

// ---------------------------------------------------------------------------
// GEMM: Y(f32, M x 256) = X(f32 M x 256) @ W(f32 256x256) + bias
// 128x128 tile, BK=32, 8x8 per thread.
// ---------------------------------------------------------------------------
__global__ __launch_bounds__(256) void gemm_proj(
    const float* __restrict__ X, const float* __restrict__ W,
    const float* __restrict__ bias, float* __restrict__ Y)
{
  __shared__ float Xs[32][132];   // [k][m]
  __shared__ float Ws[32][132];   // [k][n]
  const int t = threadIdx.x;
  const int tm = t >> 4, tn = t & 15;
  const int m0 = blockIdx.x * 128, n0 = blockIdx.y * 128;
  float acc[8][8];
#pragma unroll
  for (int i = 0; i < 8; ++i)
#pragma unroll
    for (int j = 0; j < 8; ++j) acc[i][j] = 0.f;

  for (int k0 = 0; k0 < 256; k0 += 32) {
#pragma unroll
    for (int i = 0; i < 4; ++i) {
      int idx = t + i * 256;            // 0..1023
      int r = idx >> 3, c4 = (idx & 7) << 2;
      float4 v = *reinterpret_cast<const float4*>(X + (size_t)(m0 + r) * 256 + k0 + c4);
      Xs[c4 + 0][r] = v.x; Xs[c4 + 1][r] = v.y; Xs[c4 + 2][r] = v.z; Xs[c4 + 3][r] = v.w;
    }
#pragma unroll
    for (int i = 0; i < 4; ++i) {
      int idx = t + i * 256;            // 0..1023
      int r = idx >> 5, c4 = (idx & 31) << 2;
      float4 v = *reinterpret_cast<const float4*>(W + (size_t)(k0 + r) * 256 + n0 + c4);
      Ws[r][c4 + 0] = v.x; Ws[r][c4 + 1] = v.y; Ws[r][c4 + 2] = v.z; Ws[r][c4 + 3] = v.w;
    }
    __syncthreads();
#pragma unroll
    for (int kk = 0; kk < 32; ++kk) {
      float a[8], b[8];
      *reinterpret_cast<float4*>(&a[0]) = *reinterpret_cast<const float4*>(&Xs[kk][tm * 4]);
      *reinterpret_cast<float4*>(&a[4]) = *reinterpret_cast<const float4*>(&Xs[kk][tm * 4 + 64]);
      *reinterpret_cast<float4*>(&b[0]) = *reinterpret_cast<const float4*>(&Ws[kk][tn * 4]);
      *reinterpret_cast<float4*>(&b[4]) = *reinterpret_cast<const float4*>(&Ws[kk][tn * 4 + 64]);
#pragma unroll
      for (int i = 0; i < 8; ++i)
#pragma unroll
        for (int j = 0; j < 8; ++j) acc[i][j] = fmaf(a[i], b[j], acc[i][j]);
    }
    __syncthreads();
  }
#pragma unroll
  for (int i = 0; i < 8; ++i) {
    int m = m0 + ((i < 4) ? (tm * 4 + i) : (64 + tm * 4 + i - 4));
#pragma unroll
    for (int jj = 0; jj < 2; ++jj) {
      int n = n0 + (jj == 0 ? tn * 4 : 64 + tn * 4);
      float4 bb = *reinterpret_cast<const float4*>(bias + n);
      float4 ov;
      ov.x = acc[i][jj * 4 + 0] + bb.x;
      ov.y = acc[i][jj * 4 + 1] + bb.y;
      ov.z = acc[i][jj * 4 + 2] + bb.z;
      ov.w = acc[i][jj * 4 + 3] + bb.w;
      *reinterpret_cast<float4*>(Y + (size_t)m * 256 + n) = ov;
    }
  }
}

// ---------------------------------------------------------------------------
// Fused attention: per (b,h) block, online-softmax over 16-wide K tiles.
// ctx_out may alias Q or V: every buffer access is column-sliced by head, and
// within a block all reads precede the end-of-kernel writes.
// BOTH=1: scores = fq.fk + pq.pk (Q rows reloaded per tile to bound VGPRs).
// ---------------------------------------------------------------------------
template<int BOTH>
__global__ __launch_bounds__(256) void attn_kernel(
    const float* __restrict__ Qf, const float* __restrict__ Kf,
    const float* __restrict__ Qp, const float* __restrict__ Kp,
    const float* __restrict__ V, const float* __restrict__ mask,
    float* __restrict__ ctx_out)
{
  __shared__ float k1t[16][64];
  __shared__ float k2t[BOTH ? 16 : 1][64];
  __shared__ float vt[16][64];
  __shared__ float mt[16];
  const int b = blockIdx.y, h = blockIdx.x;
  const int t = threadIdx.x;
  const int q = t;
  const size_t qbase = ((size_t)b * 200 + (q < 200 ? q : 0)) * 256 + (size_t)h * 64;
  float qreg[64], ctx[64];
#pragma unroll
  for (int d = 0; d < 64; ++d) ctx[d] = 0.f;
  float mrun = -1e30f, lrun = 0.f;
  if (!BOTH && q < 200) {
#pragma unroll
    for (int d4 = 0; d4 < 64; d4 += 4)
      *reinterpret_cast<float4*>(&qreg[d4]) = *reinterpret_cast<const float4*>(Qf + qbase + d4);
  }
  for (int kt = 0; kt < 200; kt += 16) {
    const int kn = (200 - kt < 16) ? (200 - kt) : 16;
    {
      const int r = t >> 4, c4 = (t & 15) << 2;
      if (r < kn) {
        const size_t src = ((size_t)b * 200 + kt + r) * 256 + (size_t)h * 64 + c4;
        *reinterpret_cast<float4*>(&k1t[r][c4]) = *reinterpret_cast<const float4*>(Kf + src);
        if (BOTH) *reinterpret_cast<float4*>(&k2t[r][c4]) = *reinterpret_cast<const float4*>(Kp + src);
        *reinterpret_cast<float4*>(&vt[r][c4]) = *reinterpret_cast<const float4*>(V + src);
      }
      if (t < 16) mt[t] = (kt + t < 200) ? mask[(size_t)b * 200 + kt + t] : -1e30f;
    }
    __syncthreads();
    if (q < 200) {
      float sv[16];
      if (BOTH) {
#pragma unroll
        for (int d4 = 0; d4 < 64; d4 += 4)
          *reinterpret_cast<float4*>(&qreg[d4]) = *reinterpret_cast<const float4*>(Qf + qbase + d4);
#pragma unroll
        for (int j = 0; j < 16; ++j) {
          float a = 0.f;
#pragma unroll
          for (int d = 0; d < 64; ++d) a = fmaf(qreg[d], k1t[j][d], a);
          sv[j] = a;
        }
#pragma unroll
        for (int d4 = 0; d4 < 64; d4 += 4)
          *reinterpret_cast<float4*>(&qreg[d4]) = *reinterpret_cast<const float4*>(Qp + qbase + d4);
#pragma unroll
        for (int j = 0; j < 16; ++j) {
          float a = sv[j];
#pragma unroll
          for (int d = 0; d < 64; ++d) a = fmaf(qreg[d], k2t[j][d], a);
          sv[j] = a;
        }
      } else {
#pragma unroll
        for (int j = 0; j < 16; ++j) {
          float a = 0.f;
#pragma unroll
          for (int d = 0; d < 64; ++d) a = fmaf(qreg[d], k1t[j][d], a);
          sv[j] = a;
        }
      }
      // stale rows (last tile, j >= kn) get mt = -1e30 -> p = 0 exactly
      float tmax = -1e30f;
#pragma unroll
      for (int j = 0; j < 16; ++j) { sv[j] = sv[j] * 0.125f + mt[j]; tmax = fmaxf(tmax, sv[j]); }
      const float mnew = fmaxf(mrun, tmax);
      const float scale = __expf(mrun - mnew);
      lrun *= scale;
#pragma unroll
      for (int d = 0; d < 64; ++d) ctx[d] *= scale;
#pragma unroll
      for (int j = 0; j < 16; ++j) {
        const float p = __expf(sv[j] - mnew);
        lrun += p;
#pragma unroll
        for (int d = 0; d < 64; ++d) ctx[d] = fmaf(p, vt[j][d], ctx[d]);
      }
      mrun = mnew;
    }
    __syncthreads();
  }
  if (q < 200) {
    const float inv = 1.0f / lrun;
#pragma unroll
    for (int d4 = 0; d4 < 64; d4 += 4) {
      float4 o;
      o.x = ctx[d4 + 0] * inv; o.y = ctx[d4 + 1] * inv;
      o.z = ctx[d4 + 2] * inv; o.w = ctx[d4 + 3] * inv;
      *reinterpret_cast<float4*>(ctx_out + qbase + d4) = o;
    }
  }
}

// ---------------------------------------------------------------------------
// Fused dense + residual + LayerNorm. BM=64, BN=256 (full row per block).
// Microtile 4 rows x 16 cols; LN via 16-lane shfl reduction (threads sharing
// tm are 16 consecutive lanes of one wave). In-place X==out is safe: each
// block reads only its own 64 rows, all reads precede epilogue writes.
// ---------------------------------------------------------------------------
__global__ __launch_bounds__(256) void dense_ln_kernel(
    const float* __restrict__ X, const float* __restrict__ W,
    const float* __restrict__ bias, const float* __restrict__ resid,
    const float* __restrict__ gv, const float* __restrict__ bv,
    float* __restrict__ out)
{
  __shared__ float Xs[32][68];     // [k][m]
  __shared__ float Ws[32][260];    // [k][n]
  const int t = threadIdx.x;
  const int m0 = blockIdx.x * 64;
  const int tm = t >> 4, tn = t & 15;
  float acc[4][16];
#pragma unroll
  for (int r = 0; r < 4; ++r)
#pragma unroll
    for (int c = 0; c < 16; ++c) acc[r][c] = 0.f;

  for (int k0 = 0; k0 < 256; k0 += 32) {
#pragma unroll
    for (int i = 0; i < 2; ++i) {
      int idx = t + i * 256;          // 0..511
      int r = idx >> 3, c4 = (idx & 7) << 2;
      float4 v = *reinterpret_cast<const float4*>(X + (size_t)(m0 + r) * 256 + k0 + c4);
      Xs[c4 + 0][r] = v.x; Xs[c4 + 1][r] = v.y; Xs[c4 + 2][r] = v.z; Xs[c4 + 3][r] = v.w;
    }
#pragma unroll
    for (int i = 0; i < 8; ++i) {
      int idx = t + i * 256;          // 0..2047
      int r = idx >> 6, c4 = (idx & 63) << 2;
      float4 v = *reinterpret_cast<const float4*>(W + (size_t)(k0 + r) * 256 + c4);
      Ws[r][c4 + 0] = v.x; Ws[r][c4 + 1] = v.y; Ws[r][c4 + 2] = v.z; Ws[r][c4 + 3] = v.w;
    }
    __syncthreads();
#pragma unroll
    for (int kk = 0; kk < 32; ++kk) {
      float a[4], b[16];
      *reinterpret_cast<float4*>(a) = *reinterpret_cast<const float4*>(&Xs[kk][tm * 4]);
#pragma unroll
      for (int ch = 0; ch < 4; ++ch)
        *reinterpret_cast<float4*>(&b[ch * 4]) =
            *reinterpret_cast<const float4*>(&Ws[kk][ch * 64 + tn * 4]);
#pragma unroll
      for (int r = 0; r < 4; ++r)
#pragma unroll
        for (int c = 0; c < 16; ++c) acc[r][c] = fmaf(a[r], b[c], acc[r][c]);
    }
    __syncthreads();
  }
  // + bias + resid
#pragma unroll
  for (int r = 0; r < 4; ++r) {
    int m = m0 + tm * 4 + r;
#pragma unroll
    for (int ch = 0; ch < 4; ++ch) {
      int n = ch * 64 + tn * 4;
      float4 rr = *reinterpret_cast<const float4*>(resid + (size_t)m * 256 + n);
      float4 bb = *reinterpret_cast<const float4*>(bias + n);
      acc[r][ch * 4 + 0] += rr.x + bb.x;
      acc[r][ch * 4 + 1] += rr.y + bb.y;
      acc[r][ch * 4 + 2] += rr.z + bb.z;
      acc[r][ch * 4 + 3] += rr.w + bb.w;
    }
  }
  // LayerNorm per row via 16-lane shfl groups
#pragma unroll
  for (int r = 0; r < 4; ++r) {
    float s = 0.f;
#pragma unroll
    for (int c = 0; c < 16; ++c) s += acc[r][c];
    s += __shfl_xor(s, 1); s += __shfl_xor(s, 2);
    s += __shfl_xor(s, 4); s += __shfl_xor(s, 8);
    const float mean = s * (1.0f / 256.0f);
    float vs = 0.f;
#pragma unroll
    for (int c = 0; c < 16; ++c) { float d = acc[r][c] - mean; vs += d * d; }
    vs += __shfl_xor(vs, 1); vs += __shfl_xor(vs, 2);
    vs += __shfl_xor(vs, 4); vs += __shfl_xor(vs, 8);
    const float rstd = rsqrtf(vs * (1.0f / 256.0f) + 1e-12f);
    int m = m0 + tm * 4 + r;
#pragma unroll
    for (int ch = 0; ch < 4; ++ch) {
      int n = ch * 64 + tn * 4;
      float4 gg = *reinterpret_cast<const float4*>(gv + n);
      float4 be = *reinterpret_cast<const float4*>(bv + n);
      float4 ov;
      ov.x = (acc[r][ch * 4 + 0] - mean) * rstd * gg.x + be.x;
      ov.y = (acc[r][ch * 4 + 1] - mean) * rstd * gg.y + be.y;
      ov.z = (acc[r][ch * 4 + 2] - mean) * rstd * gg.z + be.z;
      ov.w = (acc[r][ch * 4 + 3] - mean) * rstd * gg.w + be.w;
      *reinterpret_cast<float4*>(out + (size_t)m * 256 + n) = ov;
    }
  }
}

// ---------------------------------------------------------------------------
// HIE: hr[b,r,d] = sum_n h[b,n,d] * Wr[n,r]   (double accumulate)
// ---------------------------------------------------------------------------
__global__ __launch_bounds__(256) void hie_hr_kernel(
    const float* __restrict__ h, const float* __restrict__ Wr, float* __restrict__ hr)
{
  __shared__ float wrs[3200];
  const int b = blockIdx.x, t = threadIdx.x;
  for (int i = t; i < 3200; i += 256) wrs[i] = Wr[i];
  __syncthreads();
  double acc[16];
#pragma unroll
  for (int r = 0; r < 16; ++r) acc[r] = 0.0;
  const float* hb = h + (size_t)b * 200 * 256;
  for (int n = 0; n < 200; ++n) {
    float hv = hb[(size_t)n * 256 + t];
#pragma unroll
    for (int r = 0; r < 16; ++r) acc[r] += (double)(hv * wrs[n * 16 + r]);
  }
#pragma unroll
  for (int r = 0; r < 16; ++r) hr[((size_t)b * 16 + r) * 256 + t] = (float)acc[r];
}

// ---------------------------------------------------------------------------
// HIE: modified Gram-Schmidt QR of hr^T (256x16) per batch; double reductions.
// Column-sign differences vs LAPACK are invariant under the downstream gate.
// ---------------------------------------------------------------------------
__global__ __launch_bounds__(256) void hie_qr_kernel(
    const float* __restrict__ hr, float* __restrict__ Qg)
{
  __shared__ float Qs[16][256];
  __shared__ double red[4];
  const int b = blockIdx.x, t = threadIdx.x;
  const int wid = t >> 6, lane = t & 63;
  const float* A = hr + (size_t)b * 4096;
#pragma unroll 1
  for (int j = 0; j < 16; ++j) {
    double v = (double)A[j * 256 + t];
#pragma unroll 1
    for (int i = 0; i < j; ++i) {
      float qi = Qs[i][t];
      double p = (double)qi * v;
#pragma unroll
      for (int off = 32; off; off >>= 1) p += __shfl_xor(p, off);
      if (lane == 0) red[wid] = p;
      __syncthreads();
      double dot = red[0] + red[1] + red[2] + red[3];
      __syncthreads();
      v -= dot * (double)qi;
    }
    double nn = v * v;
#pragma unroll
    for (int off = 32; off; off >>= 1) nn += __shfl_xor(nn, off);
    if (lane == 0) red[wid] = nn;
    __syncthreads();
    double nrm = sqrt(red[0] + red[1] + red[2] + red[3]);
    __syncthreads();
    float qv = (float)(v / nrm);
    Qs[j][t] = qv;
    Qg[(size_t)b * 4096 + j * 256 + t] = qv;
    __syncthreads();
  }
}

// ---------------------------------------------------------------------------
// HIE: p = X @ Q (per batch). GATE: out = (pxin * p > 0) ? p : 0.
// ---------------------------------------------------------------------------
template<bool GATE>
__global__ __launch_bounds__(256) void hie_px_kernel(
    const float* __restrict__ X, const float* __restrict__ Qg,
    const float* __restrict__ pxin, float* __restrict__ outp)
{
  __shared__ float Qs[16][260];
  __shared__ float ht[16][260];
  const int b = blockIdx.x, t = threadIdx.x;
  for (int i = t; i < 4096; i += 256) Qs[i >> 8][i & 255] = Qg[(size_t)b * 4096 + i];
  const int nl = t >> 4, r = t & 15;
  for (int chunk = 0; chunk < 200; chunk += 16) {
    __syncthreads();
#pragma unroll
    for (int i = 0; i < 4; ++i) {
      int c = t + i * 256;
      int rr = c >> 6, c4 = (c & 63) << 2;
      int n = chunk + rr;
      if (n < 200)
        *reinterpret_cast<float4*>(&ht[rr][c4]) =
            *reinterpret_cast<const float4*>(X + ((size_t)b * 200 + n) * 256 + c4);
    }
    __syncthreads();
    int n = chunk + nl;
    if (n < 200) {
      double acc = 0.0;
#pragma unroll
      for (int d4 = 0; d4 < 256; d4 += 4) {
        float4 hv = *reinterpret_cast<const float4*>(&ht[nl][d4]);
        float4 qv = *reinterpret_cast<const float4*>(&Qs[r][d4]);
        acc += (double)(hv.x * qv.x + hv.y * qv.y + hv.z * qv.z + hv.w * qv.w);
      }
      float a = (float)acc;
      size_t oi = ((size_t)b * 200 + n) * 16 + r;
      if (GATE) {
        float px = pxin[oi];
        outp[oi] = (px * a > 0.0f) ? a : 0.0f;
      } else {
        outp[oi] = a;
      }
    }
  }
}

// ---------------------------------------------------------------------------
// HIE: out_h = h + pAt @ Q^T   (fp32 out)
// ---------------------------------------------------------------------------
__global__ __launch_bounds__(256) void hie_final_kernel(
    const float* __restrict__ h, const float* __restrict__ pat,
    const float* __restrict__ Qg, float* __restrict__ outp)
{
  __shared__ float Qs[16][260];
  __shared__ float pt[16][16];
  const int b = blockIdx.x, t = threadIdx.x;
  for (int i = t; i < 4096; i += 256) Qs[i >> 8][i & 255] = Qg[(size_t)b * 4096 + i];
  const int nl = t >> 4, r = t & 15;
  for (int chunk = 0; chunk < 200; chunk += 16) {
    __syncthreads();
    {
      int n = chunk + nl;
      pt[nl][r] = (n < 200) ? pat[((size_t)b * 200 + n) * 16 + r] : 0.0f;
    }
    __syncthreads();
#pragma unroll 1
    for (int j = 0; j < 16; ++j) {
      int n = chunk + j;
      if (n >= 200) break;
      float acc = h[((size_t)b * 200 + n) * 256 + t];
#pragma unroll
      for (int rr = 0; rr < 16; ++rr) acc = fmaf(pt[j][rr], Qs[rr][t], acc);
      outp[((size_t)b * 200 + n) * 256 + t] = acc;
    }
  }
}

// ws-too-small diagnostic: absmax will read ~ws_size in MB at out[0].
__global__ void diag_kernel(float* out, float val, int n) {
  int i = blockIdx.x * 256 + threadIdx.x;
  if (i < n) out[i] = (i == 0) ? val : 0.0f;
}

// ---------------------------------------------------------------------------
extern "C" void kernel_launch(void* const* d_in, const int* in_sizes, int n_in,
                              void* d_out, int out_size, void* d_ws, size_t ws_size,
                              hipStream_t stream)
{
  (void)in_sizes; (void)n_in;
  const float* input  = (const float*)d_in[0];
  const float* fusion = (const float*)d_in[1];
  const float* pos    = (const float*)d_in[2];
  const float* mask   = (const float*)d_in[3];
  const float* Wv  = (const float*)d_in[4];  const float* bv  = (const float*)d_in[5];
  const float* Wqf = (const float*)d_in[6];  const float* bqf = (const float*)d_in[7];
  const float* Wkf = (const float*)d_in[8];  const float* bkf = (const float*)d_in[9];
  const float* Wvf = (const float*)d_in[10]; const float* bvf = (const float*)d_in[11];
  const float* Wqp = (const float*)d_in[12]; const float* bqp = (const float*)d_in[13];
  const float* Wkp = (const float*)d_in[14]; const float* bkp = (const float*)d_in[15];
  const float* Wvp = (const float*)d_in[16]; const float* bvp = (const float*)d_in[17];
  const float* Wd  = (const float*)d_in[18]; const float* bd  = (const float*)d_in[19];
  const float* g1  = (const float*)d_in[20]; const float* b1  = (const float*)d_in[21];
  const float* Wfd = (const float*)d_in[22]; const float* bfd = (const float*)d_in[23];
  const float* g2  = (const float*)d_in[24]; const float* b2  = (const float*)d_in[25];
  const float* Wpd = (const float*)d_in[26]; const float* bpd = (const float*)d_in[27];
  const float* g3  = (const float*)d_in[28]; const float* b3  = (const float*)d_in[29];
  const float* Wr  = (const float*)d_in[30];

  const size_t required = 2 * BSD * 4;   // 104,857,600 bytes
  if (ws_size < required) {
    diag_kernel<<<(out_size + 255) / 256, 256, 0, stream>>>(
        (float*)d_out, (float)(ws_size >> 20), out_size);
    return;
  }

  float* W0 = (float*)d_ws;
  float* W1 = W0 + BSD;
  float* O0 = (float*)d_out;          // out_h (final)
  float* O1 = O0 + BSD;               // out_hf (final)
  float* O2 = O0 + 2 * BSD;           // out_hp (final)
  // HIE smalls inside W1 (fk dead by then)
  float* hrb  = W1;                   // 1,048,576
  float* Qb   = W1 + 1048576;         // 1,048,576
  float* pxb  = W1 + 2097152;         // 819,200
  float* patb = W1 + 2916352;         // 819,200

  dim3 G(M_ / 128, 2), Blk(256);
  dim3 AG(H_, B_);
  dim3 LG(M_ / 64);

  // projections for h branch
  gemm_proj<<<G, Blk, 0, stream>>>(fusion, Wqf, bqf, W0);   // fq
  gemm_proj<<<G, Blk, 0, stream>>>(fusion, Wkf, bkf, W1);   // fk (kept for hf)
  gemm_proj<<<G, Blk, 0, stream>>>(pos,    Wqp, bqp, O0);   // pq (kept for hp)
  gemm_proj<<<G, Blk, 0, stream>>>(pos,    Wkp, bkp, O1);   // pk (kept for hp)
  gemm_proj<<<G, Blk, 0, stream>>>(input,  Wv,  bv,  O2);   // iv
  // h branch: both_scores, V=iv, resid=input -> hbuf in W0
  attn_kernel<1><<<AG, Blk, 0, stream>>>(W0, W1, O0, O1, O2, mask, O2);  // ctx over iv
  dense_ln_kernel<<<LG, Blk, 0, stream>>>(O2, Wd, bd, input, g1, b1, W0); // hbuf (fq dead)
  // hp branch: pos_scores (pq,pk reused), V=pv, resid=pos -> O2 final
  gemm_proj<<<G, Blk, 0, stream>>>(pos, Wvp, bvp, O2);      // pv
  attn_kernel<0><<<AG, Blk, 0, stream>>>(O0, O1, nullptr, nullptr, O2, mask, O2);
  dense_ln_kernel<<<LG, Blk, 0, stream>>>(O2, Wpd, bpd, pos, g3, b3, O2); // out_hp
  // hf branch: item_scores (fk reused, fq recomputed), V=fv, resid=fusion -> O1
  gemm_proj<<<G, Blk, 0, stream>>>(fusion, Wqf, bqf, O0);   // fq (pq dead)
  gemm_proj<<<G, Blk, 0, stream>>>(fusion, Wvf, bvf, O1);   // fv (pk dead)
  attn_kernel<0><<<AG, Blk, 0, stream>>>(O0, W1, nullptr, nullptr, O1, mask, O1);
  dense_ln_kernel<<<LG, Blk, 0, stream>>>(O1, Wfd, bfd, fusion, g2, b2, O1); // out_hf
  // HIE: hbuf=W0; smalls in W1 (fk dead now)
  hie_hr_kernel<<<B_, Blk, 0, stream>>>(W0, Wr, hrb);
  hie_qr_kernel<<<B_, Blk, 0, stream>>>(hrb, Qb);
  hie_px_kernel<false><<<B_, Blk, 0, stream>>>(W0, Qb, nullptr, pxb);
  hie_px_kernel<true><<<B_, Blk, 0, stream>>>(O1, Qb, pxb, patb);
  hie_final_kernel<<<B_, Blk, 0, stream>>>(W0, patb, Qb, O0);  // out_h
}